// Round 1
// baseline (380.361 us; speedup 1.0000x reference)
//
#include <hip/hip_runtime.h>
#include <cstdint>
#include <cstddef>

#define DEV __device__ __forceinline__

DEV float sigmoidf_(float x) { return 1.0f / (1.0f + expf(-x)); }

// ---------------- ws layout (float offsets) ----------------
constexpr size_t ACC   = 0;                 // 64  (2 tracks x (16 sum + 16 sumsq))
constexpr size_t LO    = 128;               // 65536  Lo[64][128][8]
constexpr size_t RO    = LO + 65536;        // 65536  Ro[64][128][8]
constexpr size_t HBUF  = RO + 65536;        // 262144 h[track][8192][16]
constexpr size_t XW0   = HBUF + 262144;     // 393216 xw0[8192][48]
constexpr size_t ZLAST = XW0 + 393216;      // 1024   zlast[64][16]
constexpr size_t DACT  = ZLAST + 1024;      // 1024   dec act[64][16]

// ================= K1: gate GRU (2 layers, H=8) + softmax =================
__global__ __launch_bounds__(64) void k1_gate(
    const float* __restrict__ Local, const float* __restrict__ Remote,
    const float* __restrict__ Wih0, const float* __restrict__ Whh0,
    const float* __restrict__ bih0, const float* __restrict__ bhh0,
    const float* __restrict__ Wih1, const float* __restrict__ Whh1,
    const float* __restrict__ bih1, const float* __restrict__ bhh1,
    float* __restrict__ ws)
{
    const int tid = threadIdx.x;
    const int sl = tid >> 3, j = tid & 7;
    const int blk = blockIdx.x;
    const int track = blk >> 3;            // blocks 0-7: Local, 8-15: Remote
    const int b0 = (blk & 7) * 8;
    if (blk == 0 && tid < 64) ws[ACC + tid] = 0.f;   // zero stat accumulators

    __shared__ __align__(16) float xs[8][128][3];
    __shared__ __align__(16) float h0all[8][128][8];

    const float* __restrict__ src = track ? Remote : Local;
    for (int i = tid; i < 3072; i += 64) {
        int s = i / 384, rem = i - s * 384;
        int t = rem / 3, c = rem - t * 3;
        xs[s][t][c] = src[((size_t)(b0 + s) * 128 + t) * 132 + 128 + c];
    }

    // layer-0 weights for this lane's hidden unit j
    float wi0[3][3], bi0[3], wh0[3][8], bh0[3];
#pragma unroll
    for (int g = 0; g < 3; ++g) {
        int row = g * 8 + j;
#pragma unroll
        for (int c = 0; c < 3; ++c) wi0[g][c] = Wih0[row * 3 + c];
        bi0[g] = bih0[row];
#pragma unroll
        for (int k = 0; k < 8; ++k) wh0[g][k] = Whh0[row * 8 + k];
        bh0[g] = bhh0[row];
    }
    __syncthreads();

    float hk[8];
#pragma unroll
    for (int k = 0; k < 8; ++k) hk[k] = 0.f;
    float hown = 0.f;
    for (int t = 0; t < 128; ++t) {
        float x0 = xs[sl][t][0], x1 = xs[sl][t][1], x2 = xs[sl][t][2];
        float ir = bi0[0] + wi0[0][0]*x0 + wi0[0][1]*x1 + wi0[0][2]*x2;
        float iz = bi0[1] + wi0[1][0]*x0 + wi0[1][1]*x1 + wi0[1][2]*x2;
        float in_= bi0[2] + wi0[2][0]*x0 + wi0[2][1]*x1 + wi0[2][2]*x2;
        float dr = bh0[0], dz = bh0[1], dn = bh0[2];
#pragma unroll
        for (int k = 0; k < 8; ++k) {
            dr = fmaf(wh0[0][k], hk[k], dr);
            dz = fmaf(wh0[1][k], hk[k], dz);
            dn = fmaf(wh0[2][k], hk[k], dn);
        }
        float r = sigmoidf_(ir + dr);
        float z = sigmoidf_(iz + dz);
        float n = tanhf(in_ + r * dn);
        hown = (1.f - z) * n + z * hown;
        h0all[sl][t][j] = hown;
#pragma unroll
        for (int k = 0; k < 8; ++k) hk[k] = __shfl(hown, k, 8);
    }
    __syncthreads();

    // layer-1 weights
    float wi1[3][8], bi1[3], wh1[3][8], bh1[3];
#pragma unroll
    for (int g = 0; g < 3; ++g) {
        int row = g * 8 + j;
#pragma unroll
        for (int k = 0; k < 8; ++k) {
            wi1[g][k] = Wih1[row * 8 + k];
            wh1[g][k] = Whh1[row * 8 + k];
        }
        bi1[g] = bih1[row];
        bh1[g] = bhh1[row];
    }

#pragma unroll
    for (int k = 0; k < 8; ++k) hk[k] = 0.f;
    hown = 0.f;
    for (int t = 0; t < 128; ++t) {
        float xv[8];
#pragma unroll
        for (int k = 0; k < 8; ++k) xv[k] = h0all[sl][t][k];
        float ir = bi1[0], iz = bi1[1], in_ = bi1[2];
        float dr = bh1[0], dz = bh1[1], dn = bh1[2];
#pragma unroll
        for (int k = 0; k < 8; ++k) {
            ir = fmaf(wi1[0][k], xv[k], ir);
            iz = fmaf(wi1[1][k], xv[k], iz);
            in_= fmaf(wi1[2][k], xv[k], in_);
            dr = fmaf(wh1[0][k], hk[k], dr);
            dz = fmaf(wh1[1][k], hk[k], dz);
            dn = fmaf(wh1[2][k], hk[k], dn);
        }
        float r = sigmoidf_(ir + dr);
        float z = sigmoidf_(iz + dz);
        float n = tanhf(in_ + r * dn);
        hown = (1.f - z) * n + z * hown;
        __syncthreads();                 // all lanes read row t before overwrite
        h0all[sl][t][j] = hown;          // overwrite input with layer-1 output
#pragma unroll
        for (int k = 0; k < 8; ++k) hk[k] = __shfl(hown, k, 8);
    }
    __syncthreads();

    // softmax post-phase over all (seq, t)
    float* __restrict__ outp = ws + (track ? RO : LO);
    for (int i = tid; i < 1024; i += 64) {
        int s = i >> 7, t = i & 127;
        float v[8];
#pragma unroll
        for (int k = 0; k < 8; ++k) v[k] = h0all[s][t][k];
        float mx = v[0];
#pragma unroll
        for (int k = 1; k < 8; ++k) mx = fmaxf(mx, v[k]);
        float ssum = 0.f;
#pragma unroll
        for (int k = 0; k < 8; ++k) { v[k] = expf(v[k] - mx); ssum += v[k]; }
        float inv = 1.f / ssum;
        size_t base = ((size_t)(b0 + s) * 128 + t) * 8;
#pragma unroll
        for (int k = 0; k < 8; ++k) outp[base + k] = v[k] * inv;
    }
}

// ====== K2: expert layer-1 GEMM + gate mix + batch-stat accumulation ======
__global__ __launch_bounds__(256) void k2_expert1(
    const float* __restrict__ Local, const float* __restrict__ Remote,
    const float* __restrict__ ae_w1, const float* __restrict__ ae_b1,
    float* __restrict__ ws)
{
    const int blk = blockIdx.x;
    const int track = blk >> 7;
    const int n0 = (blk & 127) * 64;
    const float* __restrict__ X = track ? Remote : Local;
    const float* __restrict__ om = ws + (track ? RO : LO);

    __shared__ __align__(16) float xsh[64][64];
    __shared__ __align__(16) float wsh[16 * 516];   // [hh][e][64], padded stride
    __shared__ float omsh[64][8];
    __shared__ float b1sh[128];
    __shared__ float red[32];
    const int tid = threadIdx.x;

    for (int i = tid; i < 512; i += 256) omsh[i >> 3][i & 7] = om[(size_t)(n0 + (i >> 3)) * 8 + (i & 7)];
    for (int i = tid; i < 128; i += 256) b1sh[i] = ae_b1[i];
    if (tid < 32) red[tid] = 0.f;

    const int hh = tid & 15, rg = tid >> 4;   // rg in 0..15, 4 rows each
    float acc[4][8];
#pragma unroll
    for (int r = 0; r < 4; ++r)
#pragma unroll
        for (int e = 0; e < 8; ++e) acc[r][e] = 0.f;

    for (int kb = 0; kb < 2; ++kb) {
        __syncthreads();
        for (int i = tid; i < 4096; i += 256) {
            int r = i >> 6, k = i & 63;
            xsh[r][k] = X[(size_t)(n0 + r) * 132 + kb * 64 + k];
        }
        for (int i = tid; i < 8192; i += 256) {
            int h = i >> 9, e = (i >> 6) & 7, k = i & 63;
            wsh[h * 516 + e * 64 + k] = ae_w1[((size_t)e * 128 + kb * 64 + k) * 16 + h];
        }
        __syncthreads();
#pragma unroll 4
        for (int kq = 0; kq < 16; ++kq) {
            float4 xv[4], wv[8];
#pragma unroll
            for (int r = 0; r < 4; ++r) xv[r] = *(const float4*)&xsh[rg * 4 + r][kq * 4];
#pragma unroll
            for (int e = 0; e < 8; ++e) wv[e] = *(const float4*)&wsh[hh * 516 + e * 64 + kq * 4];
#pragma unroll
            for (int r = 0; r < 4; ++r)
#pragma unroll
                for (int e = 0; e < 8; ++e) {
                    float a = acc[r][e];
                    a = fmaf(xv[r].x, wv[e].x, a);
                    a = fmaf(xv[r].y, wv[e].y, a);
                    a = fmaf(xv[r].z, wv[e].z, a);
                    a = fmaf(xv[r].w, wv[e].w, a);
                    acc[r][e] = a;
                }
        }
    }

    // gate mix + write h + stats
    float s = 0.f, s2 = 0.f;
    float* __restrict__ hout = ws + HBUF + (size_t)track * 131072;
#pragma unroll
    for (int r = 0; r < 4; ++r) {
        int row = rg * 4 + r;
        float hv = 0.f;
#pragma unroll
        for (int e = 0; e < 8; ++e) hv = fmaf(omsh[row][e], acc[r][e] + b1sh[e * 16 + hh], hv);
        hout[(size_t)(n0 + row) * 16 + hh] = hv;
        s += hv; s2 += hv * hv;
    }
    __syncthreads();
    atomicAdd(&red[hh], s);
    atomicAdd(&red[16 + hh], s2);
    __syncthreads();
    if (tid < 32) atomicAdd(&ws[ACC + track * 32 + tid], red[tid]);
}

// ====== K3: BN finalize + ELU + expert layer-2 + Z=ZL+ZR + xW0 transform ======
__global__ __launch_bounds__(256) void k3_bn_mlp2(
    const float* __restrict__ ae_w2, const float* __restrict__ ae_b2,
    const float* __restrict__ ae_g, const float* __restrict__ ae_bt,
    const float* __restrict__ mWih0, const float* __restrict__ mbih0,
    float* __restrict__ ws)
{
    const int n0 = blockIdx.x * 64;
    const int tid = threadIdx.x;
    __shared__ float actsh[2][64][16];
    __shared__ float omsh[2][64][8];
    __shared__ float w2sh[2048];
    __shared__ float b2sh[128];
    __shared__ float zsh[64][17];
    __shared__ float wihsh[48][17];
    __shared__ float bihsh[48];
    __shared__ float stat[4][16];   // meanL, invL, meanR, invR

    if (tid < 32) {
        int trk = tid >> 4, h = tid & 15;
        float s = ws[ACC + trk * 32 + h], s2 = ws[ACC + trk * 32 + 16 + h];
        float m = s * (1.f / 8192.f);
        float v = fmaxf(s2 * (1.f / 8192.f) - m * m, 0.f);
        stat[trk * 2][h] = m;
        stat[trk * 2 + 1][h] = rsqrtf(v + 1e-5f);
    }
    for (int i = tid; i < 2048; i += 256) w2sh[i] = ae_w2[i];
    for (int i = tid; i < 128; i += 256) b2sh[i] = ae_b2[i];
    for (int i = tid; i < 768; i += 256) wihsh[i >> 4][i & 15] = mWih0[i];
    if (tid < 48) bihsh[tid] = mbih0[tid];
    for (int i = tid; i < 1024; i += 256) {
        int trk = i >> 9, r = (i >> 3) & 63, e = i & 7;
        omsh[trk][r][e] = ws[(trk ? RO : LO) + (size_t)(n0 + r) * 8 + e];
    }
    __syncthreads();

    for (int i = tid; i < 2048; i += 256) {
        int trk = i >> 10, r = (i >> 4) & 63, h = i & 15;
        float v = ws[HBUF + (size_t)trk * 131072 + (size_t)(n0 + r) * 16 + h];
        float a = ae_g[h] * (v - stat[trk * 2][h]) * stat[trk * 2 + 1][h] + ae_bt[h];
        actsh[trk][r][h] = a > 0.f ? a : expm1f(a);
    }
    __syncthreads();

    for (int i = tid; i < 1024; i += 256) {
        int r = i >> 4, o = i & 15;
        float accv = 0.f;
#pragma unroll
        for (int trk = 0; trk < 2; ++trk) {
#pragma unroll
            for (int e = 0; e < 8; ++e) {
                const float* w = &w2sh[e * 256 + o];
                float t = b2sh[e * 16 + o];
#pragma unroll
                for (int h = 0; h < 16; ++h) t = fmaf(actsh[trk][r][h], w[h * 16], t);
                accv = fmaf(omsh[trk][r][e], t, accv);
            }
        }
        zsh[r][o] = accv;
    }
    __syncthreads();

    for (int i = tid; i < 3072; i += 256) {
        int r = i / 48, gr = i - r * 48;
        float a = bihsh[gr];
#pragma unroll
        for (int k = 0; k < 16; ++k) a = fmaf(zsh[r][k], wihsh[gr][k], a);
        ws[XW0 + (size_t)(n0 + r) * 48 + gr] = a;
    }
}

// ================= K4: main GRU (2 layers, H=16) =================
__global__ __launch_bounds__(64) void k4_maingru(
    const float* __restrict__ Whh0, const float* __restrict__ bhh0,
    const float* __restrict__ Wih1, const float* __restrict__ bih1,
    const float* __restrict__ Whh1, const float* __restrict__ bhh1,
    float* __restrict__ ws)
{
    const int tid = threadIdx.x;
    const int sl = tid >> 4, j = tid & 15;
    const int seq = blockIdx.x * 4 + sl;
    __shared__ __align__(16) float h0all[4][128][16];

    float wh0[3][16], bh0[3];
#pragma unroll
    for (int g = 0; g < 3; ++g) {
        int row = g * 16 + j;
#pragma unroll
        for (int k = 0; k < 16; ++k) wh0[g][k] = Whh0[row * 16 + k];
        bh0[g] = bhh0[row];
    }
    const float* __restrict__ xw = ws + XW0 + (size_t)seq * 6144;
    float hk[16];
#pragma unroll
    for (int k = 0; k < 16; ++k) hk[k] = 0.f;
    float hown = 0.f;
    float xc0 = xw[j], xc1 = xw[16 + j], xc2 = xw[32 + j];
    for (int t = 0; t < 128; ++t) {
        float xn0 = 0.f, xn1 = 0.f, xn2 = 0.f;
        if (t < 127) {
            const float* p = xw + (t + 1) * 48;
            xn0 = p[j]; xn1 = p[16 + j]; xn2 = p[32 + j];
        }
        float dr = bh0[0], dz = bh0[1], dn = bh0[2];
#pragma unroll
        for (int k = 0; k < 16; ++k) {
            dr = fmaf(wh0[0][k], hk[k], dr);
            dz = fmaf(wh0[1][k], hk[k], dz);
            dn = fmaf(wh0[2][k], hk[k], dn);
        }
        float r = sigmoidf_(xc0 + dr);
        float z = sigmoidf_(xc1 + dz);
        float n = tanhf(xc2 + r * dn);
        hown = (1.f - z) * n + z * hown;
        h0all[sl][t][j] = hown;
#pragma unroll
        for (int k = 0; k < 16; ++k) hk[k] = __shfl(hown, k, 16);
        xc0 = xn0; xc1 = xn1; xc2 = xn2;
    }
    __syncthreads();

    float wi1[3][16], bi1[3], wh1[3][16], bh1[3];
#pragma unroll
    for (int g = 0; g < 3; ++g) {
        int row = g * 16 + j;
#pragma unroll
        for (int k = 0; k < 16; ++k) {
            wi1[g][k] = Wih1[row * 16 + k];
            wh1[g][k] = Whh1[row * 16 + k];
        }
        bi1[g] = bih1[row];
        bh1[g] = bhh1[row];
    }
#pragma unroll
    for (int k = 0; k < 16; ++k) hk[k] = 0.f;
    hown = 0.f;
    for (int t = 0; t < 128; ++t) {
        float xv[16];
#pragma unroll
        for (int k = 0; k < 16; ++k) xv[k] = h0all[sl][t][k];
        float ir = bi1[0], iz = bi1[1], in_ = bi1[2];
        float dr = bh1[0], dz = bh1[1], dn = bh1[2];
#pragma unroll
        for (int k = 0; k < 16; ++k) {
            ir = fmaf(wi1[0][k], xv[k], ir);
            iz = fmaf(wi1[1][k], xv[k], iz);
            in_= fmaf(wi1[2][k], xv[k], in_);
            dr = fmaf(wh1[0][k], hk[k], dr);
            dz = fmaf(wh1[1][k], hk[k], dz);
            dn = fmaf(wh1[2][k], hk[k], dn);
        }
        float r = sigmoidf_(ir + dr);
        float z = sigmoidf_(iz + dz);
        float n = tanhf(in_ + r * dn);
        hown = (1.f - z) * n + z * hown;
#pragma unroll
        for (int k = 0; k < 16; ++k) hk[k] = __shfl(hown, k, 16);
    }
    ws[ZLAST + (size_t)seq * 16 + j] = hown;
}

// ================= K5a: decoder layer-1 + BN + ELU =================
__global__ __launch_bounds__(256) void k5a_dec1(
    const float* __restrict__ Remote,
    const float* __restrict__ md_w1, const float* __restrict__ md_b1,
    const float* __restrict__ md_g, const float* __restrict__ md_bt,
    float* __restrict__ ws)
{
    const int tid = threadIdx.x;
    __shared__ float xsh[64][17];
    __shared__ float omsh[64][8];
    __shared__ float w1sh[2176];
    __shared__ float b1sh[128];
    __shared__ float hsh[64][17];
    __shared__ float ssum[16], ss2[16], mstat[2][16];

    for (int i = tid; i < 1024; i += 256) xsh[i >> 4][i & 15] = ws[ZLAST + i];
    if (tid < 64) xsh[tid][16] = Remote[((size_t)tid * 128 + 127) * 132 + 131];
    for (int i = tid; i < 512; i += 256)
        omsh[i >> 3][i & 7] = ws[RO + ((size_t)(i >> 3) * 128 + 127) * 8 + (i & 7)];
    for (int i = tid; i < 2176; i += 256) w1sh[i] = md_w1[i];
    for (int i = tid; i < 128; i += 256) b1sh[i] = md_b1[i];
    if (tid < 16) { ssum[tid] = 0.f; ss2[tid] = 0.f; }
    __syncthreads();

    for (int i = tid; i < 1024; i += 256) {
        int b = i >> 4, h = i & 15;
        float accv = 0.f;
#pragma unroll
        for (int e = 0; e < 8; ++e) {
            float t = b1sh[e * 16 + h];
            const float* w = &w1sh[e * 272 + h];
#pragma unroll
            for (int i2 = 0; i2 < 17; ++i2) t = fmaf(xsh[b][i2], w[i2 * 16], t);
            accv = fmaf(omsh[b][e], t, accv);
        }
        hsh[b][h] = accv;
        atomicAdd(&ssum[h], accv);
        atomicAdd(&ss2[h], accv * accv);
    }
    __syncthreads();
    if (tid < 16) {
        float m = ssum[tid] * (1.f / 64.f);
        float v = fmaxf(ss2[tid] * (1.f / 64.f) - m * m, 0.f);
        mstat[0][tid] = m;
        mstat[1][tid] = rsqrtf(v + 1e-5f);
    }
    __syncthreads();
    for (int i = tid; i < 1024; i += 256) {
        int b = i >> 4, h = i & 15;
        float a = md_g[h] * (hsh[b][h] - mstat[0][h]) * mstat[1][h] + md_bt[h];
        ws[DACT + i] = a > 0.f ? a : expm1f(a);
    }
}

// ================= K5b: decoder layer-2 -> output =================
__global__ __launch_bounds__(256) void k5b_dec2(
    const float* __restrict__ md_w2, const float* __restrict__ md_b2,
    const float* __restrict__ ws, float* __restrict__ out)
{
    const int o0 = blockIdx.x * 8;
    const int tid = threadIdx.x;
    __shared__ float actsh[64][17];
    __shared__ float omsh[64][8];
    __shared__ float w2sh[8][16][8];
    __shared__ float b2sh[8][8];

    for (int i = tid; i < 1024; i += 256) actsh[i >> 4][i & 15] = ws[DACT + i];
    for (int i = tid; i < 512; i += 256)
        omsh[i >> 3][i & 7] = ws[RO + ((size_t)(i >> 3) * 128 + 127) * 8 + (i & 7)];
    for (int i = tid; i < 1024; i += 256) {
        int e = i >> 7, h = (i >> 3) & 15, oo = i & 7;
        w2sh[e][h][oo] = md_w2[((size_t)e * 16 + h) * 128 + o0 + oo];
    }
    if (tid < 64) b2sh[tid >> 3][tid & 7] = md_b2[(size_t)(tid >> 3) * 128 + o0 + (tid & 7)];
    __syncthreads();

    for (int i = tid; i < 512; i += 256) {
        int b = i >> 3, oo = i & 7;
        float accv = 0.f;
#pragma unroll
        for (int e = 0; e < 8; ++e) {
            float t = b2sh[e][oo];
#pragma unroll
            for (int h = 0; h < 16; ++h) t = fmaf(actsh[b][h], w2sh[e][h][oo], t);
            accv = fmaf(omsh[b][e], t, accv);
        }
        out[(size_t)b * 128 + o0 + oo] = accv;
    }
}

extern "C" void kernel_launch(void* const* d_in, const int* in_sizes, int n_in,
                              void* d_out, int out_size, void* d_ws, size_t ws_size,
                              hipStream_t stream) {
    const float* Local  = (const float*)d_in[0];
    const float* Remote = (const float*)d_in[1];
    const float* gWih0  = (const float*)d_in[2];
    const float* gWhh0  = (const float*)d_in[3];
    const float* gbih0  = (const float*)d_in[4];
    const float* gbhh0  = (const float*)d_in[5];
    const float* gWih1  = (const float*)d_in[6];
    const float* gWhh1  = (const float*)d_in[7];
    const float* gbih1  = (const float*)d_in[8];
    const float* gbhh1  = (const float*)d_in[9];
    const float* mWih0  = (const float*)d_in[10];
    const float* mWhh0  = (const float*)d_in[11];
    const float* mbih0  = (const float*)d_in[12];
    const float* mbhh0  = (const float*)d_in[13];
    const float* mWih1  = (const float*)d_in[14];
    const float* mWhh1  = (const float*)d_in[15];
    const float* mbih1  = (const float*)d_in[16];
    const float* mbhh1  = (const float*)d_in[17];
    const float* ae_w1  = (const float*)d_in[18];
    const float* ae_b1  = (const float*)d_in[19];
    const float* ae_w2  = (const float*)d_in[20];
    const float* ae_b2  = (const float*)d_in[21];
    const float* ae_g   = (const float*)d_in[22];
    const float* ae_bt  = (const float*)d_in[23];
    const float* md_w1  = (const float*)d_in[24];
    const float* md_b1  = (const float*)d_in[25];
    const float* md_w2  = (const float*)d_in[26];
    const float* md_b2  = (const float*)d_in[27];
    const float* md_g   = (const float*)d_in[28];
    const float* md_bt  = (const float*)d_in[29];
    float* ws  = (float*)d_ws;
    float* out = (float*)d_out;

    k1_gate<<<16, 64, 0, stream>>>(Local, Remote, gWih0, gWhh0, gbih0, gbhh0,
                                   gWih1, gWhh1, gbih1, gbhh1, ws);
    k2_expert1<<<256, 256, 0, stream>>>(Local, Remote, ae_w1, ae_b1, ws);
    k3_bn_mlp2<<<128, 256, 0, stream>>>(ae_w2, ae_b2, ae_g, ae_bt, mWih0, mbih0, ws);
    k4_maingru<<<16, 64, 0, stream>>>(mWhh0, mbhh0, mWih1, mbih1, mWhh1, mbhh1, ws);
    k5a_dec1<<<1, 256, 0, stream>>>(Remote, md_w1, md_b1, md_g, md_bt, ws);
    k5b_dec2<<<16, 256, 0, stream>>>(md_w2, md_b2, ws, out);
}

// Round 2
// 281.156 us; speedup vs baseline: 1.3528x; 1.3528x over previous
//
#include <hip/hip_runtime.h>
#include <cstdint>
#include <cstddef>

#define DEV __device__ __forceinline__

DEV float fsig(float x)  { return __builtin_amdgcn_rcpf(1.0f + __expf(-x)); }
DEV float ftanh_(float x){ return 1.0f - 2.0f * __builtin_amdgcn_rcpf(1.0f + __expf(2.0f * x)); }

// ---------------- ws layout (float offsets) ----------------
constexpr size_t ACC   = 0;                 // 64  (2 tracks x (16 sum + 16 sumsq))
constexpr size_t LO    = 128;               // 65536  Lo[64][128][8]
constexpr size_t RO    = LO + 65536;        // 65536  Ro[64][128][8]
constexpr size_t HBUF  = RO + 65536;        // 262144 h[track][8192][16]
constexpr size_t ZBUF  = HBUF + 262144;     // 131072 Z[64][128][16]
constexpr size_t ZLAST = ZBUF + 393216;     // 1024   zlast[64][16]
constexpr size_t DACT  = ZLAST + 1024;      // 1024   dec act[64][16]

// ===== K1: gate GRU, both layers pipelined with 1-step skew + softmax =====
// 32 blocks x 64 thr. Block = 4 sequences; 16 lanes/seq: lanes 0-7 layer0
// unit j, lanes 8-15 layer1 unit j. Layer1 lags one step; depth 129 not 256.
__global__ __launch_bounds__(64) void k1_gate(
    const float* __restrict__ Local, const float* __restrict__ Remote,
    const float* __restrict__ Wih0, const float* __restrict__ Whh0,
    const float* __restrict__ bih0, const float* __restrict__ bhh0,
    const float* __restrict__ Wih1, const float* __restrict__ Whh1,
    const float* __restrict__ bih1, const float* __restrict__ bhh1,
    float* __restrict__ ws)
{
    const int tid = threadIdx.x;
    const int grp = tid >> 4;          // 4 seqs per block
    const int l16 = tid & 15;
    const int layer = l16 >> 3;
    const int j = l16 & 7;
    const int blk = blockIdx.x;
    const int track = blk >> 4;        // blocks 0-15: Local, 16-31: Remote
    const int b0 = (blk & 15) * 4;
    if (blk == 0) ws[ACC + tid] = 0.f;     // zero stat accumulators

    __shared__ __align__(16) float xs[4][128][3];
    __shared__ __align__(16) float h1all[4][128][9];   // layer1 outputs (padded)
    __shared__ __align__(16) float hbuf[4][16];        // per-group h broadcast

    const float* __restrict__ src = track ? Remote : Local;
    for (int i = tid; i < 1536; i += 64) {
        int s = i / 384, rem = i - s * 384;
        int t = rem / 3, c = rem - t * 3;
        xs[s][t][c] = src[((size_t)(b0 + s) * 128 + t) * 132 + 128 + c];
    }
    hbuf[tid >> 4][tid & 15] = 0.f;

    // weights: uniform layout, layer-dependent source (layer0 input padded 3->8)
    float wi[3][8], wh[3][8], bi[3], bh[3];
    if (layer == 0) {
#pragma unroll
        for (int g = 0; g < 3; ++g) {
            int row = g * 8 + j;
#pragma unroll
            for (int k = 0; k < 8; ++k) {
                wi[g][k] = (k < 3) ? Wih0[row * 3 + k] : 0.f;
                wh[g][k] = Whh0[row * 8 + k];
            }
            bi[g] = bih0[row]; bh[g] = bhh0[row];
        }
    } else {
#pragma unroll
        for (int g = 0; g < 3; ++g) {
            int row = g * 8 + j;
#pragma unroll
            for (int k = 0; k < 8; ++k) {
                wi[g][k] = Wih1[row * 8 + k];
                wh[g][k] = Whh1[row * 8 + k];
            }
            bi[g] = bih1[row]; bh[g] = bhh1[row];
        }
    }
    __syncthreads();

    float hown = 0.f;
#pragma unroll 1
    for (int t = 0; t <= 128; ++t) {
        float4 f0 = *(const float4*)&hbuf[grp][0];
        float4 f1 = *(const float4*)&hbuf[grp][4];
        float4 f2 = *(const float4*)&hbuf[grp][8];
        float4 f3 = *(const float4*)&hbuf[grp][12];
        float v[16] = {f0.x,f0.y,f0.z,f0.w, f1.x,f1.y,f1.z,f1.w,
                       f2.x,f2.y,f2.z,f2.w, f3.x,f3.y,f3.z,f3.w};
        float xv[8], hk[8];
        int tt = t < 128 ? t : 127;
        if (layer == 0) {
            xv[0] = xs[grp][tt][0]; xv[1] = xs[grp][tt][1]; xv[2] = xs[grp][tt][2];
            xv[3] = 0.f; xv[4] = 0.f; xv[5] = 0.f; xv[6] = 0.f; xv[7] = 0.f;
#pragma unroll
            for (int k = 0; k < 8; ++k) hk[k] = v[k];
        } else {
#pragma unroll
            for (int k = 0; k < 8; ++k) { xv[k] = v[k]; hk[k] = v[8 + k]; }
        }
        float ir = bi[0], iz = bi[1], in_ = bi[2];
        float dr = bh[0], dz = bh[1], dn = bh[2];
#pragma unroll
        for (int k = 0; k < 8; ++k) {
            ir = fmaf(wi[0][k], xv[k], ir);
            iz = fmaf(wi[1][k], xv[k], iz);
            in_= fmaf(wi[2][k], xv[k], in_);
            dr = fmaf(wh[0][k], hk[k], dr);
            dz = fmaf(wh[1][k], hk[k], dz);
            dn = fmaf(wh[2][k], hk[k], dn);
        }
        float r = fsig(ir + dr);
        float z = fsig(iz + dz);
        float n = ftanh_(in_ + r * dn);
        float hnew = (1.f - z) * n + z * hown;
        bool act = layer ? (t >= 1) : (t < 128);
        hown = act ? hnew : hown;
        __syncthreads();
        hbuf[grp][l16] = hown;
        if (layer && t >= 1) h1all[grp][t - 1][j] = hown;
        __syncthreads();
    }

    // softmax post-phase
    float* __restrict__ outp = ws + (track ? RO : LO);
    for (int i = tid; i < 512; i += 64) {
        int s = i >> 7, t = i & 127;
        float vv[8];
#pragma unroll
        for (int k = 0; k < 8; ++k) vv[k] = h1all[s][t][k];
        float mx = vv[0];
#pragma unroll
        for (int k = 1; k < 8; ++k) mx = fmaxf(mx, vv[k]);
        float ssum = 0.f;
#pragma unroll
        for (int k = 0; k < 8; ++k) { vv[k] = __expf(vv[k] - mx); ssum += vv[k]; }
        float inv = __builtin_amdgcn_rcpf(ssum);
        size_t base = ((size_t)(b0 + s) * 128 + t) * 8;
#pragma unroll
        for (int k = 0; k < 8; ++k) outp[base + k] = vv[k] * inv;
    }
}

// ====== K2: expert layer-1 GEMM + gate mix + batch-stat accumulation ======
__global__ __launch_bounds__(256) void k2_expert1(
    const float* __restrict__ Local, const float* __restrict__ Remote,
    const float* __restrict__ ae_w1, const float* __restrict__ ae_b1,
    float* __restrict__ ws)
{
    const int blk = blockIdx.x;
    const int track = blk >> 7;
    const int n0 = (blk & 127) * 64;
    const float* __restrict__ X = track ? Remote : Local;
    const float* __restrict__ om = ws + (track ? RO : LO);

    __shared__ __align__(16) float xsh[64][64];
    __shared__ __align__(16) float wsh[16 * 516];
    __shared__ float omsh[64][8];
    __shared__ float b1sh[128];
    __shared__ float red[32];
    const int tid = threadIdx.x;

    for (int i = tid; i < 512; i += 256) omsh[i >> 3][i & 7] = om[(size_t)(n0 + (i >> 3)) * 8 + (i & 7)];
    for (int i = tid; i < 128; i += 256) b1sh[i] = ae_b1[i];
    if (tid < 32) red[tid] = 0.f;

    const int hh = tid & 15, rg = tid >> 4;
    float acc[4][8];
#pragma unroll
    for (int r = 0; r < 4; ++r)
#pragma unroll
        for (int e = 0; e < 8; ++e) acc[r][e] = 0.f;

    for (int kb = 0; kb < 2; ++kb) {
        __syncthreads();
        for (int i = tid; i < 4096; i += 256) {
            int r = i >> 6, k = i & 63;
            xsh[r][k] = X[(size_t)(n0 + r) * 132 + kb * 64 + k];
        }
        for (int i = tid; i < 8192; i += 256) {
            int h = i >> 9, e = (i >> 6) & 7, k = i & 63;
            wsh[h * 516 + e * 64 + k] = ae_w1[((size_t)e * 128 + kb * 64 + k) * 16 + h];
        }
        __syncthreads();
#pragma unroll 4
        for (int kq = 0; kq < 16; ++kq) {
            float4 xv[4], wv[8];
#pragma unroll
            for (int r = 0; r < 4; ++r) xv[r] = *(const float4*)&xsh[rg * 4 + r][kq * 4];
#pragma unroll
            for (int e = 0; e < 8; ++e) wv[e] = *(const float4*)&wsh[hh * 516 + e * 64 + kq * 4];
#pragma unroll
            for (int r = 0; r < 4; ++r)
#pragma unroll
                for (int e = 0; e < 8; ++e) {
                    float a = acc[r][e];
                    a = fmaf(xv[r].x, wv[e].x, a);
                    a = fmaf(xv[r].y, wv[e].y, a);
                    a = fmaf(xv[r].z, wv[e].z, a);
                    a = fmaf(xv[r].w, wv[e].w, a);
                    acc[r][e] = a;
                }
        }
    }

    float s = 0.f, s2 = 0.f;
    float* __restrict__ hout = ws + HBUF + (size_t)track * 131072;
#pragma unroll
    for (int r = 0; r < 4; ++r) {
        int row = rg * 4 + r;
        float hv = 0.f;
#pragma unroll
        for (int e = 0; e < 8; ++e) hv = fmaf(omsh[row][e], acc[r][e] + b1sh[e * 16 + hh], hv);
        hout[(size_t)(n0 + row) * 16 + hh] = hv;
        s += hv; s2 += hv * hv;
    }
    __syncthreads();
    atomicAdd(&red[hh], s);
    atomicAdd(&red[16 + hh], s2);
    __syncthreads();
    if (tid < 32) atomicAdd(&ws[ACC + track * 32 + tid], red[tid]);
}

// ====== K3: BN finalize + ELU + expert layer-2 + Z=ZL+ZR ======
__global__ __launch_bounds__(256) void k3_bn_mlp2(
    const float* __restrict__ ae_w2, const float* __restrict__ ae_b2,
    const float* __restrict__ ae_g, const float* __restrict__ ae_bt,
    float* __restrict__ ws)
{
    const int n0 = blockIdx.x * 64;
    const int tid = threadIdx.x;
    __shared__ float actsh[2][64][16];
    __shared__ float omsh[2][64][8];
    __shared__ float w2sh[2048];
    __shared__ float b2sh[128];
    __shared__ float stat[4][16];

    if (tid < 32) {
        int trk = tid >> 4, h = tid & 15;
        float s = ws[ACC + trk * 32 + h], s2 = ws[ACC + trk * 32 + 16 + h];
        float m = s * (1.f / 8192.f);
        float v = fmaxf(s2 * (1.f / 8192.f) - m * m, 0.f);
        stat[trk * 2][h] = m;
        stat[trk * 2 + 1][h] = rsqrtf(v + 1e-5f);
    }
    for (int i = tid; i < 2048; i += 256) w2sh[i] = ae_w2[i];
    for (int i = tid; i < 128; i += 256) b2sh[i] = ae_b2[i];
    for (int i = tid; i < 1024; i += 256) {
        int trk = i >> 9, r = (i >> 3) & 63, e = i & 7;
        omsh[trk][r][e] = ws[(trk ? RO : LO) + (size_t)(n0 + r) * 8 + e];
    }
    __syncthreads();

    for (int i = tid; i < 2048; i += 256) {
        int trk = i >> 10, r = (i >> 4) & 63, h = i & 15;
        float v = ws[HBUF + (size_t)trk * 131072 + (size_t)(n0 + r) * 16 + h];
        float a = ae_g[h] * (v - stat[trk * 2][h]) * stat[trk * 2 + 1][h] + ae_bt[h];
        actsh[trk][r][h] = a > 0.f ? a : expm1f(a);
    }
    __syncthreads();

    for (int i = tid; i < 1024; i += 256) {
        int r = i >> 4, o = i & 15;
        float accv = 0.f;
#pragma unroll
        for (int trk = 0; trk < 2; ++trk) {
#pragma unroll
            for (int e = 0; e < 8; ++e) {
                const float* w = &w2sh[e * 256 + o];
                float t = b2sh[e * 16 + o];
#pragma unroll
                for (int h = 0; h < 16; ++h) t = fmaf(actsh[trk][r][h], w[h * 16], t);
                accv = fmaf(omsh[trk][r][e], t, accv);
            }
        }
        ws[ZBUF + (size_t)(n0 + r) * 16 + o] = accv;
    }
}

// ===== K4: main GRU, both layers pipelined with 1-step skew =====
// 32 blocks x 64 thr. Block = 2 sequences; 32 lanes/seq: lanes 0-15 layer0,
// lanes 16-31 layer1 (lagging one step). Depth 129 not 256.
__global__ __launch_bounds__(64) void k4_maingru(
    const float* __restrict__ Wih0, const float* __restrict__ Whh0,
    const float* __restrict__ bih0, const float* __restrict__ bhh0,
    const float* __restrict__ Wih1, const float* __restrict__ Whh1,
    const float* __restrict__ bih1, const float* __restrict__ bhh1,
    float* __restrict__ ws)
{
    const int tid = threadIdx.x;
    const int grp = tid >> 5;
    const int l32 = tid & 31;
    const int layer = l32 >> 4;
    const int j = l32 & 15;
    const int seq = blockIdx.x * 2 + grp;

    __shared__ __align__(16) float zs[2][128][16];
    __shared__ __align__(16) float hbuf[2][32];

    const float* __restrict__ zsrc = ws + ZBUF + (size_t)blockIdx.x * 4096;
    for (int i = tid; i < 1024; i += 64)
        ((float4*)zs)[i] = ((const float4*)zsrc)[i];
    hbuf[tid >> 5][tid & 31] = 0.f;

    float wi[3][16], wh[3][16], bi[3], bh[3];
    if (layer == 0) {
#pragma unroll
        for (int g = 0; g < 3; ++g) {
            int row = g * 16 + j;
#pragma unroll
            for (int k = 0; k < 16; ++k) {
                wi[g][k] = Wih0[row * 16 + k];
                wh[g][k] = Whh0[row * 16 + k];
            }
            bi[g] = bih0[row]; bh[g] = bhh0[row];
        }
    } else {
#pragma unroll
        for (int g = 0; g < 3; ++g) {
            int row = g * 16 + j;
#pragma unroll
            for (int k = 0; k < 16; ++k) {
                wi[g][k] = Wih1[row * 16 + k];
                wh[g][k] = Whh1[row * 16 + k];
            }
            bi[g] = bih1[row]; bh[g] = bhh1[row];
        }
    }
    __syncthreads();

    float hown = 0.f;
#pragma unroll 1
    for (int t = 0; t <= 128; ++t) {
        float v[32];
#pragma unroll
        for (int q = 0; q < 8; ++q) {
            float4 f = *(const float4*)&hbuf[grp][q * 4];
            v[q * 4 + 0] = f.x; v[q * 4 + 1] = f.y; v[q * 4 + 2] = f.z; v[q * 4 + 3] = f.w;
        }
        float xv[16], hk[16];
        int tt = t < 128 ? t : 127;
        if (layer == 0) {
#pragma unroll
            for (int q = 0; q < 4; ++q) {
                float4 f = *(const float4*)&zs[grp][tt][q * 4];
                xv[q * 4 + 0] = f.x; xv[q * 4 + 1] = f.y; xv[q * 4 + 2] = f.z; xv[q * 4 + 3] = f.w;
            }
#pragma unroll
            for (int k = 0; k < 16; ++k) hk[k] = v[k];
        } else {
#pragma unroll
            for (int k = 0; k < 16; ++k) { xv[k] = v[k]; hk[k] = v[16 + k]; }
        }
        float ir = bi[0], iz = bi[1], in_ = bi[2];
        float dr = bh[0], dz = bh[1], dn = bh[2];
#pragma unroll
        for (int k = 0; k < 16; ++k) {
            ir = fmaf(wi[0][k], xv[k], ir);
            iz = fmaf(wi[1][k], xv[k], iz);
            in_= fmaf(wi[2][k], xv[k], in_);
            dr = fmaf(wh[0][k], hk[k], dr);
            dz = fmaf(wh[1][k], hk[k], dz);
            dn = fmaf(wh[2][k], hk[k], dn);
        }
        float r = fsig(ir + dr);
        float z = fsig(iz + dz);
        float n = ftanh_(in_ + r * dn);
        float hnew = (1.f - z) * n + z * hown;
        bool act = layer ? (t >= 1) : (t < 128);
        hown = act ? hnew : hown;
        __syncthreads();
        hbuf[grp][l32] = hown;
        __syncthreads();
    }
    if (layer) ws[ZLAST + (size_t)seq * 16 + j] = hown;
}

// ===== K5: decoder MLP fused (layer1+BN redundant per block, layer2 slice) =====
__global__ __launch_bounds__(256) void k5_dec(
    const float* __restrict__ Remote,
    const float* __restrict__ md_w1, const float* __restrict__ md_b1,
    const float* __restrict__ md_g, const float* __restrict__ md_bt,
    const float* __restrict__ md_w2, const float* __restrict__ md_b2,
    const float* __restrict__ ws, float* __restrict__ out)
{
    const int o0 = blockIdx.x * 8;
    const int tid = threadIdx.x;
    __shared__ float xsh[64][17];
    __shared__ float omsh[64][8];
    __shared__ float w1sh[2176];
    __shared__ float b1sh[128];
    __shared__ float hsh[64][17];
    __shared__ float ssum[16], ss2[16], mstat[2][16];
    __shared__ float ash[64][17];
    __shared__ float w2sh[8][16][8];
    __shared__ float b2sh[8][8];

    for (int i = tid; i < 1024; i += 256) xsh[i >> 4][i & 15] = ws[ZLAST + i];
    if (tid < 64) xsh[tid][16] = Remote[((size_t)tid * 128 + 127) * 132 + 131];
    for (int i = tid; i < 512; i += 256)
        omsh[i >> 3][i & 7] = ws[RO + ((size_t)(i >> 3) * 128 + 127) * 8 + (i & 7)];
    for (int i = tid; i < 2176; i += 256) w1sh[i] = md_w1[i];
    for (int i = tid; i < 128; i += 256) b1sh[i] = md_b1[i];
    for (int i = tid; i < 1024; i += 256) {
        int e = i >> 7, h = (i >> 3) & 15, oo = i & 7;
        w2sh[e][h][oo] = md_w2[((size_t)e * 16 + h) * 128 + o0 + oo];
    }
    if (tid < 64) b2sh[tid >> 3][tid & 7] = md_b2[(size_t)(tid >> 3) * 128 + o0 + (tid & 7)];
    if (tid < 16) { ssum[tid] = 0.f; ss2[tid] = 0.f; }
    __syncthreads();

    for (int i = tid; i < 1024; i += 256) {
        int b = i >> 4, h = i & 15;
        float accv = 0.f;
#pragma unroll
        for (int e = 0; e < 8; ++e) {
            float t = b1sh[e * 16 + h];
            const float* w = &w1sh[e * 272 + h];
#pragma unroll
            for (int i2 = 0; i2 < 17; ++i2) t = fmaf(xsh[b][i2], w[i2 * 16], t);
            accv = fmaf(omsh[b][e], t, accv);
        }
        hsh[b][h] = accv;
        atomicAdd(&ssum[h], accv);
        atomicAdd(&ss2[h], accv * accv);
    }
    __syncthreads();
    if (tid < 16) {
        float m = ssum[tid] * (1.f / 64.f);
        float v = fmaxf(ss2[tid] * (1.f / 64.f) - m * m, 0.f);
        mstat[0][tid] = m;
        mstat[1][tid] = rsqrtf(v + 1e-5f);
    }
    __syncthreads();
    for (int i = tid; i < 1024; i += 256) {
        int b = i >> 4, h = i & 15;
        float a = md_g[h] * (hsh[b][h] - mstat[0][h]) * mstat[1][h] + md_bt[h];
        ash[b][h] = a > 0.f ? a : expm1f(a);
    }
    __syncthreads();

    for (int i = tid; i < 512; i += 256) {
        int b = i >> 3, oo = i & 7;
        float accv = 0.f;
#pragma unroll
        for (int e = 0; e < 8; ++e) {
            float t = b2sh[e][oo];
#pragma unroll
            for (int h = 0; h < 16; ++h) t = fmaf(ash[b][h], w2sh[e][h][oo], t);
            accv = fmaf(omsh[b][e], t, accv);
        }
        out[(size_t)b * 128 + o0 + oo] = accv;
    }
}

extern "C" void kernel_launch(void* const* d_in, const int* in_sizes, int n_in,
                              void* d_out, int out_size, void* d_ws, size_t ws_size,
                              hipStream_t stream) {
    const float* Local  = (const float*)d_in[0];
    const float* Remote = (const float*)d_in[1];
    const float* gWih0  = (const float*)d_in[2];
    const float* gWhh0  = (const float*)d_in[3];
    const float* gbih0  = (const float*)d_in[4];
    const float* gbhh0  = (const float*)d_in[5];
    const float* gWih1  = (const float*)d_in[6];
    const float* gWhh1  = (const float*)d_in[7];
    const float* gbih1  = (const float*)d_in[8];
    const float* gbhh1  = (const float*)d_in[9];
    const float* mWih0  = (const float*)d_in[10];
    const float* mWhh0  = (const float*)d_in[11];
    const float* mbih0  = (const float*)d_in[12];
    const float* mbhh0  = (const float*)d_in[13];
    const float* mWih1  = (const float*)d_in[14];
    const float* mWhh1  = (const float*)d_in[15];
    const float* mbih1  = (const float*)d_in[16];
    const float* mbhh1  = (const float*)d_in[17];
    const float* ae_w1  = (const float*)d_in[18];
    const float* ae_b1  = (const float*)d_in[19];
    const float* ae_w2  = (const float*)d_in[20];
    const float* ae_b2  = (const float*)d_in[21];
    const float* ae_g   = (const float*)d_in[22];
    const float* ae_bt  = (const float*)d_in[23];
    const float* md_w1  = (const float*)d_in[24];
    const float* md_b1  = (const float*)d_in[25];
    const float* md_w2  = (const float*)d_in[26];
    const float* md_b2  = (const float*)d_in[27];
    const float* md_g   = (const float*)d_in[28];
    const float* md_bt  = (const float*)d_in[29];
    float* ws  = (float*)d_ws;
    float* out = (float*)d_out;

    k1_gate<<<32, 64, 0, stream>>>(Local, Remote, gWih0, gWhh0, gbih0, gbhh0,
                                   gWih1, gWhh1, gbih1, gbhh1, ws);
    k2_expert1<<<256, 256, 0, stream>>>(Local, Remote, ae_w1, ae_b1, ws);
    k3_bn_mlp2<<<128, 256, 0, stream>>>(ae_w2, ae_b2, ae_g, ae_bt, ws);
    k4_maingru<<<32, 64, 0, stream>>>(mWih0, mWhh0, mbih0, mbhh0,
                                      mWih1, mWhh1, mbih1, mbhh1, ws);
    k5_dec<<<16, 256, 0, stream>>>(Remote, md_w1, md_b1, md_g, md_bt,
                                   md_w2, md_b2, ws, out);
}

// Round 3
// 254.547 us; speedup vs baseline: 1.4943x; 1.1045x over previous
//
#include <hip/hip_runtime.h>
#include <cstdint>
#include <cstddef>

#define DEV __device__ __forceinline__

typedef float v2f __attribute__((ext_vector_type(2)));

DEV float fsig(float x)  { return __builtin_amdgcn_rcpf(1.0f + __expf(-x)); }
DEV float ftanh_(float x){ return 1.0f - 2.0f * __builtin_amdgcn_rcpf(1.0f + __expf(2.0f * x)); }
DEV float readlanef(float v, int l) {
    return __uint_as_float(__builtin_amdgcn_readlane(__float_as_uint(v), l));
}
DEV float bpermf(float v, int byteidx) {
    return __uint_as_float(__builtin_amdgcn_ds_bpermute(byteidx, __float_as_uint(v)));
}
DEV v2f fma2v(v2f a, float b, v2f c) {
    return (v2f){ fmaf(a.x, b, c.x), fmaf(a.y, b, c.y) };
}

// ---------------- ws layout (float offsets) ----------------
constexpr size_t ACC   = 0;                 // 64  (2 tracks x (16 sum + 16 sumsq))
constexpr size_t LO    = 128;               // 65536  Lo[64][128][8]
constexpr size_t RO    = LO + 65536;        // 65536  Ro[64][128][8]
constexpr size_t HBUF  = RO + 65536;        // 262144 h[track][8192][16]
constexpr size_t XW0   = HBUF + 262144;     // 393216 xw0[8192][48]
constexpr size_t ZLAST = XW0 + 393216;      // 1024   zlast[64][16]

// ===== K1: gate GRU, 1 seq/wave, skewed layers, readlane broadcast =====
// 128 blocks x 64 thr. Lanes: j=tid&7, layer=(tid>>3)&1 (lanes 0-15 hold
// state; 16-63 are harmless duplicates). vb slots: [h0(8)|h1(8)|x(3)].
__global__ __launch_bounds__(64) void k1_gate(
    const float* __restrict__ Local, const float* __restrict__ Remote,
    const float* __restrict__ Wih0, const float* __restrict__ Whh0,
    const float* __restrict__ bih0, const float* __restrict__ bhh0,
    const float* __restrict__ Wih1, const float* __restrict__ Whh1,
    const float* __restrict__ bih1, const float* __restrict__ bhh1,
    float* __restrict__ ws)
{
    const int tid = threadIdx.x;
    const int j = tid & 7;
    const int layer = (tid >> 3) & 1;
    const int blk = blockIdx.x;
    const int track = blk >> 6;
    const int b = blk & 63;
    if (blk == 0) ws[ACC + tid] = 0.f;

    __shared__ __align__(16) float4 xs4[128];
    __shared__ float h1all[128][9];

    const float* __restrict__ src = track ? Remote : Local;
    for (int t = tid; t < 128; t += 64) {
        const float* p = src + ((size_t)b * 128 + t) * 132 + 128;
        xs4[t] = make_float4(p[0], p[1], p[2], 0.f);
    }

    v2f wrz[19], wnn[19];
    float base_r, base_z, base_in, base_dn;
    if (layer == 0) {
#pragma unroll
        for (int k = 0; k < 8; ++k) {
            wrz[k] = (v2f){ Whh0[j * 8 + k], Whh0[(8 + j) * 8 + k] };
            wnn[k] = (v2f){ 0.f, Whh0[(16 + j) * 8 + k] };
            wrz[8 + k] = (v2f){0.f, 0.f};
            wnn[8 + k] = (v2f){0.f, 0.f};
        }
#pragma unroll
        for (int c = 0; c < 3; ++c) {
            wrz[16 + c] = (v2f){ Wih0[j * 3 + c], Wih0[(8 + j) * 3 + c] };
            wnn[16 + c] = (v2f){ Wih0[(16 + j) * 3 + c], 0.f };
        }
        base_r = bih0[j] + bhh0[j];
        base_z = bih0[8 + j] + bhh0[8 + j];
        base_in = bih0[16 + j];
        base_dn = bhh0[16 + j];
    } else {
#pragma unroll
        for (int k = 0; k < 8; ++k) {
            wrz[k] = (v2f){ Wih1[j * 8 + k], Wih1[(8 + j) * 8 + k] };
            wnn[k] = (v2f){ Wih1[(16 + j) * 8 + k], 0.f };
            wrz[8 + k] = (v2f){ Whh1[j * 8 + k], Whh1[(8 + j) * 8 + k] };
            wnn[8 + k] = (v2f){ 0.f, Whh1[(16 + j) * 8 + k] };
        }
#pragma unroll
        for (int c = 0; c < 3; ++c) {
            wrz[16 + c] = (v2f){0.f, 0.f};
            wnn[16 + c] = (v2f){0.f, 0.f};
        }
        base_r = bih1[j] + bhh1[j];
        base_z = bih1[8 + j] + bhh1[8 + j];
        base_in = bih1[16 + j];
        base_dn = bhh1[16 + j];
    }
    __syncthreads();   // once: xs4 staged

    float hown = 0.f;
    float4 xc = xs4[0];
#pragma unroll 1
    for (int t = 0; t <= 128; ++t) {
        float4 xn = xs4[t < 127 ? t + 1 : 127];    // prefetch, off critical path
        float vb[16];
#pragma unroll
        for (int k = 0; k < 16; ++k) vb[k] = readlanef(hown, k);
        v2f arz = (v2f){ base_r, base_z };
        v2f ann = (v2f){ base_in, base_dn };
#pragma unroll
        for (int k = 0; k < 16; ++k) {
            arz = fma2v(wrz[k], vb[k], arz);
            ann = fma2v(wnn[k], vb[k], ann);
        }
        arz = fma2v(wrz[16], xc.x, arz); ann = fma2v(wnn[16], xc.x, ann);
        arz = fma2v(wrz[17], xc.y, arz); ann = fma2v(wnn[17], xc.y, ann);
        arz = fma2v(wrz[18], xc.z, arz); ann = fma2v(wnn[18], xc.z, ann);
        float r = fsig(arz.x);
        float z = fsig(arz.y);
        float n = ftanh_(ann.x + r * ann.y);
        float hnew = (1.f - z) * n + z * hown;
        bool act = layer ? (t >= 1) : (t < 128);
        hown = act ? hnew : hown;
        if (tid >= 8 && tid < 16 && t >= 1) h1all[t - 1][j] = hown;
        xc = xn;
    }
    __syncthreads();

    // softmax over layer-1 outputs
    float* __restrict__ outp = ws + (track ? RO : LO);
    for (int t = tid; t < 128; t += 64) {
        float vv[8];
#pragma unroll
        for (int k = 0; k < 8; ++k) vv[k] = h1all[t][k];
        float mx = vv[0];
#pragma unroll
        for (int k = 1; k < 8; ++k) mx = fmaxf(mx, vv[k]);
        float ssum = 0.f;
#pragma unroll
        for (int k = 0; k < 8; ++k) { vv[k] = __expf(vv[k] - mx); ssum += vv[k]; }
        float inv = __builtin_amdgcn_rcpf(ssum);
        size_t base = ((size_t)b * 128 + t) * 8;
        float4 o0 = make_float4(vv[0] * inv, vv[1] * inv, vv[2] * inv, vv[3] * inv);
        float4 o1 = make_float4(vv[4] * inv, vv[5] * inv, vv[6] * inv, vv[7] * inv);
        *(float4*)(outp + base) = o0;
        *(float4*)(outp + base + 4) = o1;
    }
}

// ====== K2: expert layer-1 GEMM + gate mix + batch-stat accumulation ======
__global__ __launch_bounds__(256) void k2_expert1(
    const float* __restrict__ Local, const float* __restrict__ Remote,
    const float* __restrict__ ae_w1, const float* __restrict__ ae_b1,
    float* __restrict__ ws)
{
    const int blk = blockIdx.x;
    const int track = blk >> 7;
    const int n0 = (blk & 127) * 64;
    const float* __restrict__ X = track ? Remote : Local;
    const float* __restrict__ om = ws + (track ? RO : LO);

    __shared__ __align__(16) float xsh[64][64];
    __shared__ __align__(16) float wsh[16 * 516];
    __shared__ float omsh[64][8];
    __shared__ float b1sh[128];
    __shared__ float red[32];
    const int tid = threadIdx.x;

    for (int i = tid; i < 512; i += 256) omsh[i >> 3][i & 7] = om[(size_t)(n0 + (i >> 3)) * 8 + (i & 7)];
    for (int i = tid; i < 128; i += 256) b1sh[i] = ae_b1[i];
    if (tid < 32) red[tid] = 0.f;

    const int hh = tid & 15, rg = tid >> 4;
    float acc[4][8];
#pragma unroll
    for (int r = 0; r < 4; ++r)
#pragma unroll
        for (int e = 0; e < 8; ++e) acc[r][e] = 0.f;

    for (int kb = 0; kb < 2; ++kb) {
        __syncthreads();
        for (int i = tid; i < 4096; i += 256) {
            int r = i >> 6, k = i & 63;
            xsh[r][k] = X[(size_t)(n0 + r) * 132 + kb * 64 + k];
        }
        for (int i = tid; i < 8192; i += 256) {
            int h = i >> 9, e = (i >> 6) & 7, k = i & 63;
            wsh[h * 516 + e * 64 + k] = ae_w1[((size_t)e * 128 + kb * 64 + k) * 16 + h];
        }
        __syncthreads();
#pragma unroll 4
        for (int kq = 0; kq < 16; ++kq) {
            float4 xv[4], wv[8];
#pragma unroll
            for (int r = 0; r < 4; ++r) xv[r] = *(const float4*)&xsh[rg * 4 + r][kq * 4];
#pragma unroll
            for (int e = 0; e < 8; ++e) wv[e] = *(const float4*)&wsh[hh * 516 + e * 64 + kq * 4];
#pragma unroll
            for (int r = 0; r < 4; ++r)
#pragma unroll
                for (int e = 0; e < 8; ++e) {
                    float a = acc[r][e];
                    a = fmaf(xv[r].x, wv[e].x, a);
                    a = fmaf(xv[r].y, wv[e].y, a);
                    a = fmaf(xv[r].z, wv[e].z, a);
                    a = fmaf(xv[r].w, wv[e].w, a);
                    acc[r][e] = a;
                }
        }
    }

    float s = 0.f, s2 = 0.f;
    float* __restrict__ hout = ws + HBUF + (size_t)track * 131072;
#pragma unroll
    for (int r = 0; r < 4; ++r) {
        int row = rg * 4 + r;
        float hv = 0.f;
#pragma unroll
        for (int e = 0; e < 8; ++e) hv = fmaf(omsh[row][e], acc[r][e] + b1sh[e * 16 + hh], hv);
        hout[(size_t)(n0 + row) * 16 + hh] = hv;
        s += hv; s2 += hv * hv;
    }
    __syncthreads();
    atomicAdd(&red[hh], s);
    atomicAdd(&red[16 + hh], s2);
    __syncthreads();
    if (tid < 32) atomicAdd(&ws[ACC + track * 32 + tid], red[tid]);
}

// ====== K3: BN finalize + ELU + expert layer-2 + Z=ZL+ZR + xw0 precompute ======
__global__ __launch_bounds__(256) void k3_bn_mlp2(
    const float* __restrict__ ae_w2, const float* __restrict__ ae_b2,
    const float* __restrict__ ae_g, const float* __restrict__ ae_bt,
    const float* __restrict__ mWih0, const float* __restrict__ mbih0,
    float* __restrict__ ws)
{
    const int n0 = blockIdx.x * 64;
    const int tid = threadIdx.x;
    __shared__ float actsh[2][64][16];
    __shared__ float omsh[2][64][8];
    __shared__ float w2sh[2048];
    __shared__ float b2sh[128];
    __shared__ float zsh[64][17];
    __shared__ float wihsh[48][17];
    __shared__ float bihsh[48];
    __shared__ float stat[4][16];

    if (tid < 32) {
        int trk = tid >> 4, h = tid & 15;
        float s = ws[ACC + trk * 32 + h], s2 = ws[ACC + trk * 32 + 16 + h];
        float m = s * (1.f / 8192.f);
        float v = fmaxf(s2 * (1.f / 8192.f) - m * m, 0.f);
        stat[trk * 2][h] = m;
        stat[trk * 2 + 1][h] = rsqrtf(v + 1e-5f);
    }
    for (int i = tid; i < 2048; i += 256) w2sh[i] = ae_w2[i];
    for (int i = tid; i < 128; i += 256) b2sh[i] = ae_b2[i];
    for (int i = tid; i < 768; i += 256) wihsh[i >> 4][i & 15] = mWih0[i];
    if (tid < 48) bihsh[tid] = mbih0[tid];
    for (int i = tid; i < 1024; i += 256) {
        int trk = i >> 9, r = (i >> 3) & 63, e = i & 7;
        omsh[trk][r][e] = ws[(trk ? RO : LO) + (size_t)(n0 + r) * 8 + e];
    }
    __syncthreads();

    for (int i = tid; i < 2048; i += 256) {
        int trk = i >> 10, r = (i >> 4) & 63, h = i & 15;
        float v = ws[HBUF + (size_t)trk * 131072 + (size_t)(n0 + r) * 16 + h];
        float a = ae_g[h] * (v - stat[trk * 2][h]) * stat[trk * 2 + 1][h] + ae_bt[h];
        actsh[trk][r][h] = a > 0.f ? a : expm1f(a);
    }
    __syncthreads();

    for (int i = tid; i < 1024; i += 256) {
        int r = i >> 4, o = i & 15;
        float accv = 0.f;
#pragma unroll
        for (int trk = 0; trk < 2; ++trk) {
#pragma unroll
            for (int e = 0; e < 8; ++e) {
                const float* w = &w2sh[e * 256 + o];
                float t = b2sh[e * 16 + o];
#pragma unroll
                for (int h = 0; h < 16; ++h) t = fmaf(actsh[trk][r][h], w[h * 16], t);
                accv = fmaf(omsh[trk][r][e], t, accv);
            }
        }
        zsh[r][o] = accv;
    }
    __syncthreads();

    // xw0[n][48] = bih0 + Wih0 . Z[n]
    for (int i = tid; i < 3072; i += 256) {
        int r = i / 48, gr = i - r * 48;
        float a = bihsh[gr];
#pragma unroll
        for (int k = 0; k < 16; ++k) a = fmaf(zsh[r][k], wihsh[gr][k], a);
        ws[XW0 + (size_t)(n0 + r) * 48 + gr] = a;
    }
}

// ===== K4: main GRU, 1 seq/wave, skewed layers, bpermute broadcast, k-split =====
// 64 blocks x 64 thr. Lanes: j=tid&15, layer=(tid>>4)&1, half=tid>>5.
// half0 sums k-slots 0..15 (vb=h0), half1 sums 16..31 (vb=h1); butterfly-xor32
// combine gives all lanes the full sums. Layer0 input transform precomputed (xw0).
__global__ __launch_bounds__(64) void k4_maingru(
    const float* __restrict__ Whh0, const float* __restrict__ bhh0,
    const float* __restrict__ Wih1, const float* __restrict__ Whh1,
    const float* __restrict__ bih1, const float* __restrict__ bhh1,
    float* __restrict__ ws)
{
    const int tid = threadIdx.x;
    const int j = tid & 15;
    const int layer = (tid >> 4) & 1;
    const int half = tid >> 5;
    const int seq = blockIdx.x;

    __shared__ __align__(16) float4 xw4[1536];   // xw0[128][48] staged
    float* xwsh = (float*)xw4;

    const float4* __restrict__ xsrc = (const float4*)(ws + XW0 + (size_t)seq * 6144);
    for (int i = tid; i < 1536; i += 64) xw4[i] = xsrc[i];

    v2f wrz[16], wnn[16];
    float base_r, base_z, base_in, base_dn;
    if (layer == 0) {
        if (half == 0) {
#pragma unroll
            for (int k = 0; k < 16; ++k) {
                wrz[k] = (v2f){ Whh0[j * 16 + k], Whh0[(16 + j) * 16 + k] };
                wnn[k] = (v2f){ 0.f, Whh0[(32 + j) * 16 + k] };
            }
        } else {
#pragma unroll
            for (int k = 0; k < 16; ++k) { wrz[k] = (v2f){0.f,0.f}; wnn[k] = (v2f){0.f,0.f}; }
        }
        base_r = half ? 0.f : bhh0[j];
        base_z = half ? 0.f : bhh0[16 + j];
        base_in = 0.f;                       // xw0 carries bih0 + Wih0.z
        base_dn = half ? 0.f : bhh0[32 + j];
    } else {
        if (half == 0) {
#pragma unroll
            for (int k = 0; k < 16; ++k) {
                wrz[k] = (v2f){ Wih1[j * 16 + k], Wih1[(16 + j) * 16 + k] };
                wnn[k] = (v2f){ Wih1[(32 + j) * 16 + k], 0.f };
            }
        } else {
#pragma unroll
            for (int k = 0; k < 16; ++k) {
                wrz[k] = (v2f){ Whh1[j * 16 + k], Whh1[(16 + j) * 16 + k] };
                wnn[k] = (v2f){ 0.f, Whh1[(32 + j) * 16 + k] };
            }
        }
        base_r = half ? 0.f : (bih1[j] + bhh1[j]);
        base_z = half ? 0.f : (bih1[16 + j] + bhh1[16 + j]);
        base_in = half ? 0.f : bih1[32 + j];
        base_dn = half ? 0.f : bhh1[32 + j];
    }
    const float m0f = (layer == 0 && half == 0) ? 1.f : 0.f;
    const int ibase = half << 6;             // bpermute byte base: lanes 0..15 / 16..31
    const int lid = __builtin_amdgcn_mbcnt_hi(~0u, __builtin_amdgcn_mbcnt_lo(~0u, 0u));
    const int pidx = (lid ^ 32) << 2;
    __syncthreads();   // once: xw0 staged

    float hown = 0.f;
    float p0 = xwsh[j], p1 = xwsh[16 + j], p2 = xwsh[32 + j];
#pragma unroll 1
    for (int t = 0; t <= 128; ++t) {
        int tn = (t < 127 ? t + 1 : 127) * 48;
        float q0 = xwsh[tn + j], q1 = xwsh[tn + 16 + j], q2 = xwsh[tn + 32 + j];
        float vb[16];
#pragma unroll
        for (int k = 0; k < 16; ++k) vb[k] = bpermf(hown, ibase + 4 * k);
        v2f arz = (v2f){ fmaf(m0f, p0, base_r), fmaf(m0f, p1, base_z) };
        v2f ann = (v2f){ fmaf(m0f, p2, base_in), base_dn };
#pragma unroll
        for (int k = 0; k < 16; ++k) {
            arz = fma2v(wrz[k], vb[k], arz);
            ann = fma2v(wnn[k], vb[k], ann);
        }
        float sr = arz.x + bpermf(arz.x, pidx);
        float sz = arz.y + bpermf(arz.y, pidx);
        float si = ann.x + bpermf(ann.x, pidx);
        float sd = ann.y + bpermf(ann.y, pidx);
        float r = fsig(sr);
        float z = fsig(sz);
        float n = ftanh_(si + r * sd);
        float hnew = (1.f - z) * n + z * hown;
        bool act = layer ? (t >= 1) : (t < 128);
        hown = act ? hnew : hown;
        p0 = q0; p1 = q1; p2 = q2;
    }
    if (tid >= 16 && tid < 32) ws[ZLAST + (size_t)seq * 16 + j] = hown;
}

// ===== K5: decoder MLP fused (layer1+BN redundant per block, layer2 slice) =====
__global__ __launch_bounds__(256) void k5_dec(
    const float* __restrict__ Remote,
    const float* __restrict__ md_w1, const float* __restrict__ md_b1,
    const float* __restrict__ md_g, const float* __restrict__ md_bt,
    const float* __restrict__ md_w2, const float* __restrict__ md_b2,
    const float* __restrict__ ws, float* __restrict__ out)
{
    const int o0 = blockIdx.x * 8;
    const int tid = threadIdx.x;
    __shared__ float xsh[64][17];
    __shared__ float omsh[64][8];
    __shared__ float w1sh[2176];
    __shared__ float b1sh[128];
    __shared__ float hsh[64][17];
    __shared__ float ssum[16], ss2[16], mstat[2][16];
    __shared__ float ash[64][17];
    __shared__ float w2sh[8][16][8];
    __shared__ float b2sh[8][8];

    for (int i = tid; i < 1024; i += 256) xsh[i >> 4][i & 15] = ws[ZLAST + i];
    if (tid < 64) xsh[tid][16] = Remote[((size_t)tid * 128 + 127) * 132 + 131];
    for (int i = tid; i < 512; i += 256)
        omsh[i >> 3][i & 7] = ws[RO + ((size_t)(i >> 3) * 128 + 127) * 8 + (i & 7)];
    for (int i = tid; i < 2176; i += 256) w1sh[i] = md_w1[i];
    for (int i = tid; i < 128; i += 256) b1sh[i] = md_b1[i];
    for (int i = tid; i < 1024; i += 256) {
        int e = i >> 7, h = (i >> 3) & 15, oo = i & 7;
        w2sh[e][h][oo] = md_w2[((size_t)e * 16 + h) * 128 + o0 + oo];
    }
    if (tid < 64) b2sh[tid >> 3][tid & 7] = md_b2[(size_t)(tid >> 3) * 128 + o0 + (tid & 7)];
    if (tid < 16) { ssum[tid] = 0.f; ss2[tid] = 0.f; }
    __syncthreads();

    for (int i = tid; i < 1024; i += 256) {
        int b = i >> 4, h = i & 15;
        float accv = 0.f;
#pragma unroll
        for (int e = 0; e < 8; ++e) {
            float t = b1sh[e * 16 + h];
            const float* w = &w1sh[e * 272 + h];
#pragma unroll
            for (int i2 = 0; i2 < 17; ++i2) t = fmaf(xsh[b][i2], w[i2 * 16], t);
            accv = fmaf(omsh[b][e], t, accv);
        }
        hsh[b][h] = accv;
        atomicAdd(&ssum[h], accv);
        atomicAdd(&ss2[h], accv * accv);
    }
    __syncthreads();
    if (tid < 16) {
        float m = ssum[tid] * (1.f / 64.f);
        float v = fmaxf(ss2[tid] * (1.f / 64.f) - m * m, 0.f);
        mstat[0][tid] = m;
        mstat[1][tid] = rsqrtf(v + 1e-5f);
    }
    __syncthreads();
    for (int i = tid; i < 1024; i += 256) {
        int b = i >> 4, h = i & 15;
        float a = md_g[h] * (hsh[b][h] - mstat[0][h]) * mstat[1][h] + md_bt[h];
        ash[b][h] = a > 0.f ? a : expm1f(a);
    }
    __syncthreads();

    for (int i = tid; i < 512; i += 256) {
        int b = i >> 3, oo = i & 7;
        float accv = 0.f;
#pragma unroll
        for (int e = 0; e < 8; ++e) {
            float t = b2sh[e][oo];
#pragma unroll
            for (int h = 0; h < 16; ++h) t = fmaf(ash[b][h], w2sh[e][h][oo], t);
            accv = fmaf(omsh[b][e], t, accv);
        }
        out[(size_t)b * 128 + o0 + oo] = accv;
    }
}

extern "C" void kernel_launch(void* const* d_in, const int* in_sizes, int n_in,
                              void* d_out, int out_size, void* d_ws, size_t ws_size,
                              hipStream_t stream) {
    const float* Local  = (const float*)d_in[0];
    const float* Remote = (const float*)d_in[1];
    const float* gWih0  = (const float*)d_in[2];
    const float* gWhh0  = (const float*)d_in[3];
    const float* gbih0  = (const float*)d_in[4];
    const float* gbhh0  = (const float*)d_in[5];
    const float* gWih1  = (const float*)d_in[6];
    const float* gWhh1  = (const float*)d_in[7];
    const float* gbih1  = (const float*)d_in[8];
    const float* gbhh1  = (const float*)d_in[9];
    const float* mWih0  = (const float*)d_in[10];
    const float* mWhh0  = (const float*)d_in[11];
    const float* mbih0  = (const float*)d_in[12];
    const float* mbhh0  = (const float*)d_in[13];
    const float* mWih1  = (const float*)d_in[14];
    const float* mWhh1  = (const float*)d_in[15];
    const float* mbih1  = (const float*)d_in[16];
    const float* mbhh1  = (const float*)d_in[17];
    const float* ae_w1  = (const float*)d_in[18];
    const float* ae_b1  = (const float*)d_in[19];
    const float* ae_w2  = (const float*)d_in[20];
    const float* ae_b2  = (const float*)d_in[21];
    const float* ae_g   = (const float*)d_in[22];
    const float* ae_bt  = (const float*)d_in[23];
    const float* md_w1  = (const float*)d_in[24];
    const float* md_b1  = (const float*)d_in[25];
    const float* md_w2  = (const float*)d_in[26];
    const float* md_b2  = (const float*)d_in[27];
    const float* md_g   = (const float*)d_in[28];
    const float* md_bt  = (const float*)d_in[29];
    float* ws  = (float*)d_ws;
    float* out = (float*)d_out;

    k1_gate<<<128, 64, 0, stream>>>(Local, Remote, gWih0, gWhh0, gbih0, gbhh0,
                                    gWih1, gWhh1, gbih1, gbhh1, ws);
    k2_expert1<<<256, 256, 0, stream>>>(Local, Remote, ae_w1, ae_b1, ws);
    k3_bn_mlp2<<<128, 256, 0, stream>>>(ae_w2, ae_b2, ae_g, ae_bt, mWih0, mbih0, ws);
    k4_maingru<<<64, 64, 0, stream>>>(mWhh0, mbhh0, mWih1, mWhh1, mbih1, mbhh1, ws);
    k5_dec<<<16, 256, 0, stream>>>(Remote, md_w1, md_b1, md_g, md_bt,
                                   md_w2, md_b2, ws, out);
}